// Round 5
// baseline (357.998 us; speedup 1.0000x reference)
//
#include <hip/hip_runtime.h>
#include <math.h>

// Problem constants (fixed by reference setup_inputs):
//   stimuli: (16,16,304,608) fp32, eye: (16,16,6) fp32, out: (16,16,304,608) fp32
#define IMG_H 304
#define IMG_W 608
#define IMG_HW (IMG_H * IMG_W)   // 184832
#define TPB 128                  // 2 waves per block, 1 16x16 tile per wave

#define TILE 16
#define TILES_X (IMG_W / TILE)      // 38
#define TILES_Y (IMG_H / TILE)      // 19
#define NTILES (TILES_X * TILES_Y)  // 722 = 361 blocks * 2 waves
#define TILES_PER_BLOCK 2

// 8-byte vector load with only 4-byte alignment guarantee (x0 is arbitrary).
typedef float f2u __attribute__((ext_vector_type(2), aligned(4)));

__global__ __launch_bounds__(TPB) void grid_sample_kernel(
    const float* __restrict__ stimuli,
    const float* __restrict__ eye,
    float* __restrict__ out)
{
    // Keep all implicit mul/add UNFUSED (hipcc device default is
    // -ffp-contract=fast-honor-pragmas). The only FMAs are the explicit
    // fmaf() calls modeling the einsum/dot accumulation chain.
    #pragma clang fp contract(off)

    // Per-wave linspace tables: one correctly-rounded f32 division per
    // entry, computed once per tile instead of per pixel.
    //   s_cx[w][c] = { rn(a0*xg(c)), rn(a3*xg(c)) }  (same bits the
    //   reference's per-pixel `a0 * xg` produces)
    //   s_yg[w][r] = yg(r)  (raw: it feeds fmaf(a1, yg, c0) as an operand)
    __shared__ float2 s_cx[TILES_PER_BLOCK][TILE];
    __shared__ float  s_yg[TILES_PER_BLOCK][TILE];

    const int bf = blockIdx.y;
    const float* __restrict__ img = stimuli + (size_t)bf * IMG_HW;
    float* __restrict__ o = out + (size_t)bf * IMG_HW;

    // Affine params (f32). Wave-uniform loads -> scalar broadcast.
    const float a0 = eye[bf * 6 + 0];
    const float a1 = eye[bf * 6 + 1];
    const float a2 = eye[bf * 6 + 2];
    const float a3 = eye[bf * 6 + 3];
    const float a4 = eye[bf * 6 + 4];
    const float a5 = eye[bf * 6 + 5];

    const int wave = threadIdx.x >> 6;
    const int lane = threadIdx.x & 63;
    const int t = blockIdx.x * TILES_PER_BLOCK + wave;   // 0..721
    const int tile_r = t / TILES_X;
    const int tile_c = t - tile_r * TILES_X;

    // jnp.linspace(-1, 1, N, dtype=f32) semantics (modern JAX):
    //   t = iota(N-1)/(N-1)  (f32 division)
    //   out = fl(t - fl(1-t)); endpoint appended exactly as 1.0f.
    if (lane < TILE) {
        const int j = tile_c * TILE + lane;
        float xg;
        if (j == IMG_W - 1) {
            xg = 1.0f;
        } else {
            const float tx = (float)j / 607.0f;       // correctly-rounded div
            xg = tx - (1.0f - tx);                    // unfused (contract off)
        }
        s_cx[wave][lane] = make_float2(a0 * xg, a3 * xg);
    } else if (lane < 2 * TILE) {
        const int r = lane - TILE;
        const int rr = tile_r * TILE + r;
        float yg;
        if (rr == IMG_H - 1) {
            yg = 1.0f;
        } else {
            const float ty = (float)rr / 303.0f;
            yg = ty - (1.0f - ty);
        }
        s_yg[wave][r] = yg;
    }
    __syncthreads();

    // Pixel-per-lane 8x8 subtiles (4 per wave = 16x16 tile). Each 64-lane
    // gather's footprint is the affine image of an 8x8 patch (~15 input
    // rows) instead of a 16x13 slab (~22 rows) — square minimizes
    // |a3|*w + |a4|*h, the distinct-line count the TA serializes on.
    const int ry = lane >> 3;   // 0..7
    const int cx = lane & 7;    // 0..7

#pragma unroll
    for (int si = 0; si < 2; ++si) {
#pragma unroll
        for (int sj = 0; sj < 2; ++sj) {
            const int row = tile_r * TILE + si * 8 + ry;
            const int col = tile_c * TILE + sj * 8 + cx;

            const float2 c0  = s_cx[wave][sj * 8 + cx];  // {a0*xg, a3*xg}
            const float  ygv = s_yg[wave][si * 8 + ry];

            // einsum 'bfij,jp->bfip' as an f32 FMA accumulation chain:
            const float xs = fmaf(a1, ygv, c0.x) + a2;
            const float ys = fmaf(a4, ygv, c0.y) + a5;

            // (x + 1.0) * W / 2.0 — separate f32 ops (div by 2 exact)
            const float x = ((xs + 1.0f) * (float)IMG_W) / 2.0f;
            const float y = ((ys + 1.0f) * (float)IMG_H) / 2.0f;

            const float fx0 = floorf(x);
            const float fy0 = floorf(y);
            const int x0 = (int)fx0;
            const int y0 = (int)fy0;

            const int x0c = min(max(x0, 0), IMG_W - 1);
            const int x1c = min(max(x0 + 1, 0), IMG_W - 1);
            const int y0c = min(max(y0, 0), IMG_H - 1);
            const int y1c = min(max(y0 + 1, 0), IMG_H - 1);

            // Paired corner loads (verified rounds 3->4, absmax identical).
            //   x0 in [0,W-2]: Ia=P0, Ic=P1
            //   x0 <  0      : both img[row,0]=P0
            //   x0 >= W-1    : xp=W-2 -> both P1
            const int xp = min(x0c, IMG_W - 2);
            const f2u ra = *reinterpret_cast<const f2u*>(img + y0c * IMG_W + xp);
            const f2u rb = *reinterpret_cast<const f2u*>(img + y1c * IMG_W + xp);

            const bool hi = (x0 >= IMG_W - 1);
            const bool lo = (x0 < 0);
            const float Ia = hi ? ra.y : ra.x;
            const float Ic = lo ? ra.x : ra.y;
            const float Ib = hi ? rb.y : rb.x;
            const float Id = lo ? rb.x : rb.y;

            const float x0f = (float)x0c, x1f = (float)x1c;
            const float y0f = (float)y0c, y1f = (float)y1c;

            // elementwise f32 weight arithmetic, unfused
            const float wxa = x1f - x;
            const float wxb = x - x0f;
            const float wya = y1f - y;
            const float wyb = y - y0f;

            const float wa = wxa * wya;
            const float wb = wxa * wyb;
            const float wc = wxb * wya;
            const float wd = wxb * wyb;

            // ((wa*Ia + wb*Ib) + wc*Ic) + wd*Id, left-assoc, unfused
            const float s0 = (wa * Ia) + (wb * Ib);
            const float s1 = s0 + (wc * Ic);
            const float rv = s1 + (wd * Id);

            // Plain store (round 4 measured: nontemporal inflated
            // WRITE_SIZE 185->232 MB; reverted).
            o[(size_t)row * IMG_W + col] = rv;
        }
    }
}

extern "C" void kernel_launch(void* const* d_in, const int* in_sizes, int n_in,
                              void* d_out, int out_size, void* d_ws, size_t ws_size,
                              hipStream_t stream) {
    const float* stimuli = (const float*)d_in[0];
    const float* eye     = (const float*)d_in[1];
    float* out           = (float*)d_out;

    const int n_imgs = in_sizes[1] / 6;              // 256
    const int blocks_x = NTILES / TILES_PER_BLOCK;   // 361
    dim3 grid(blocks_x, n_imgs);
    grid_sample_kernel<<<grid, TPB, 0, stream>>>(stimuli, eye, out);
}

// Round 6
// 353.296 us; speedup vs baseline: 1.0133x; 1.0133x over previous
//
#include <hip/hip_runtime.h>
#include <math.h>

// Problem constants (fixed by reference setup_inputs):
//   stimuli: (16,16,304,608) fp32, eye: (16,16,6) fp32, out: (16,16,304,608) fp32
#define IMG_H 304
#define IMG_W 608
#define IMG_HW (IMG_H * IMG_W)   // 184832
#define TPB 128                  // 2 waves per block, 1 16x16 tile per wave

#define TILE 16
#define TILES_X (IMG_W / TILE)      // 38
#define TILES_Y (IMG_H / TILE)      // 19
#define NTILES (TILES_X * TILES_Y)  // 722 = 361 blocks * 2 waves
#define TILES_PER_BLOCK 2

// 8-byte vector load with only 4-byte alignment guarantee (x0 is arbitrary).
typedef float f2u __attribute__((ext_vector_type(2), aligned(4)));

__global__ __launch_bounds__(TPB) void grid_sample_kernel(
    const float* __restrict__ stimuli,
    const float* __restrict__ eye,
    float* __restrict__ out)
{
    // Keep all implicit mul/add UNFUSED (hipcc device default is
    // -ffp-contract=fast-honor-pragmas). The only FMAs are the explicit
    // fmaf() calls modeling the einsum/dot accumulation chain.
    #pragma clang fp contract(off)

    // Per-wave linspace tables (verified round 5): one correctly-rounded
    // f32 division per entry, once per tile instead of per pixel.
    __shared__ float2 s_cx[TILES_PER_BLOCK][TILE];  // {rn(a0*xg), rn(a3*xg)}
    __shared__ float  s_yg[TILES_PER_BLOCK][TILE];  // yg

    const int bf = blockIdx.y;
    const float* __restrict__ img = stimuli + (size_t)bf * IMG_HW;
    float* __restrict__ o = out + (size_t)bf * IMG_HW;

    // Affine params (f32). Wave-uniform loads -> scalar broadcast.
    const float a0 = eye[bf * 6 + 0];
    const float a1 = eye[bf * 6 + 1];
    const float a2 = eye[bf * 6 + 2];
    const float a3 = eye[bf * 6 + 3];
    const float a4 = eye[bf * 6 + 4];
    const float a5 = eye[bf * 6 + 5];

    const int wave = threadIdx.x >> 6;
    const int lane = threadIdx.x & 63;
    const int t = blockIdx.x * TILES_PER_BLOCK + wave;   // 0..721
    const int tile_r = t / TILES_X;
    const int tile_c = t - tile_r * TILES_X;

    // jnp.linspace(-1, 1, N, dtype=f32) semantics (modern JAX):
    //   t = iota(N-1)/(N-1); out = fl(t - fl(1-t)); endpoint = exactly 1.0f.
    if (lane < TILE) {
        const int j = tile_c * TILE + lane;
        float xg;
        if (j == IMG_W - 1) {
            xg = 1.0f;
        } else {
            const float tx = (float)j / 607.0f;       // correctly-rounded div
            xg = tx - (1.0f - tx);                    // unfused (contract off)
        }
        s_cx[wave][lane] = make_float2(a0 * xg, a3 * xg);
    } else if (lane < 2 * TILE) {
        const int r = lane - TILE;
        const int rr = tile_r * TILE + r;
        float yg;
        if (rr == IMG_H - 1) {
            yg = 1.0f;
        } else {
            const float ty = (float)rr / 303.0f;
            yg = ty - (1.0f - ty);
        }
        s_yg[wave][r] = yg;
    }
    __syncthreads();

    // Pixel-per-lane 8x8 subtiles (verified round 5). This round's single
    // change: PHASE-SPLIT. Phase 1 computes coords/weights and ISSUES all
    // 8 paired loads into register arrays (full unroll -> static indices,
    // stays in VGPRs); phase 2 consumes. Raises per-wave outstanding
    // loads ~1.5 -> 8 to cover L1-miss/L2 latency (round-5 VGPR=24 showed
    // the compiler was consuming each load within its iteration).
    const int ry = lane >> 3;   // 0..7
    const int cx = lane & 7;    // 0..7

    f2u  ra[2][2], rb[2][2];
    float wa[2][2], wbv[2][2], wcv[2][2], wdv[2][2];
    int  x0s[2][2];

#pragma unroll
    for (int si = 0; si < 2; ++si) {
#pragma unroll
        for (int sj = 0; sj < 2; ++sj) {
            const float2 c0  = s_cx[wave][sj * 8 + cx];  // {a0*xg, a3*xg}
            const float  ygv = s_yg[wave][si * 8 + ry];

            // einsum 'bfij,jp->bfip' as an f32 FMA accumulation chain:
            const float xs = fmaf(a1, ygv, c0.x) + a2;
            const float ys = fmaf(a4, ygv, c0.y) + a5;

            // (x + 1.0) * W / 2.0 — separate f32 ops (div by 2 exact)
            const float x = ((xs + 1.0f) * (float)IMG_W) / 2.0f;
            const float y = ((ys + 1.0f) * (float)IMG_H) / 2.0f;

            const float fx0 = floorf(x);
            const float fy0 = floorf(y);
            const int x0 = (int)fx0;
            const int y0 = (int)fy0;

            const int x0c = min(max(x0, 0), IMG_W - 1);
            const int x1c = min(max(x0 + 1, 0), IMG_W - 1);
            const int y0c = min(max(y0, 0), IMG_H - 1);
            const int y1c = min(max(y0 + 1, 0), IMG_H - 1);

            // Paired corner loads (clamp-select verified rounds 4-5):
            //   x0 in [0,W-2]: Ia=P0, Ic=P1
            //   x0 <  0      : both img[row,0]=P0
            //   x0 >= W-1    : xp=W-2 -> both P1
            const int xp = min(x0c, IMG_W - 2);
            ra[si][sj] = *reinterpret_cast<const f2u*>(img + y0c * IMG_W + xp);
            rb[si][sj] = *reinterpret_cast<const f2u*>(img + y1c * IMG_W + xp);
            x0s[si][sj] = x0;

            const float x0f = (float)x0c, x1f = (float)x1c;
            const float y0f = (float)y0c, y1f = (float)y1c;

            // elementwise f32 weight arithmetic, unfused
            const float wxa = x1f - x;
            const float wxb = x - x0f;
            const float wya = y1f - y;
            const float wyb = y - y0f;

            wa[si][sj]  = wxa * wya;
            wbv[si][sj] = wxa * wyb;
            wcv[si][sj] = wxb * wya;
            wdv[si][sj] = wxb * wyb;
        }
    }

#pragma unroll
    for (int si = 0; si < 2; ++si) {
#pragma unroll
        for (int sj = 0; sj < 2; ++sj) {
            const int x0 = x0s[si][sj];
            const bool hi = (x0 >= IMG_W - 1);
            const bool lo = (x0 < 0);
            const f2u rav = ra[si][sj];
            const f2u rbv = rb[si][sj];
            const float Ia = hi ? rav.y : rav.x;
            const float Ic = lo ? rav.x : rav.y;
            const float Ib = hi ? rbv.y : rbv.x;
            const float Id = lo ? rbv.x : rbv.y;

            // ((wa*Ia + wb*Ib) + wc*Ic) + wd*Id, left-assoc, unfused
            const float s0 = (wa[si][sj] * Ia) + (wbv[si][sj] * Ib);
            const float s1 = s0 + (wcv[si][sj] * Ic);
            const float rv = s1 + (wdv[si][sj] * Id);

            const int row = tile_r * TILE + si * 8 + ry;
            const int col = tile_c * TILE + sj * 8 + cx;
            o[(size_t)row * IMG_W + col] = rv;
        }
    }
}

extern "C" void kernel_launch(void* const* d_in, const int* in_sizes, int n_in,
                              void* d_out, int out_size, void* d_ws, size_t ws_size,
                              hipStream_t stream) {
    const float* stimuli = (const float*)d_in[0];
    const float* eye     = (const float*)d_in[1];
    float* out           = (float*)d_out;

    const int n_imgs = in_sizes[1] / 6;              // 256
    const int blocks_x = NTILES / TILES_PER_BLOCK;   // 361
    dim3 grid(blocks_x, n_imgs);
    grid_sample_kernel<<<grid, TPB, 0, stream>>>(stimuli, eye, out);
}